// Round 11
// baseline (262.335 us; speedup 1.0000x reference)
//
#include <hip/hip_runtime.h>

#define BATCH 2
#define C 20
#define W 512
#define NPIX (512*512)
#define NW 16
#define NH 16
#define K 256
#define NITERS 10
#define SPLIT 4
#define PITCH 260          // LDS row pitch (floats)
#define NEG_INF_F (-1.0e10f)
#define PART_STRIDE 189    // 9 neighbors * (20 ch + 1 den)
#define SPFP 32            // padded spf row: 20 ch + sumsq@[20]

// ---------------------------------------------------------------- init
// Block = (b, cell, split), 1 px/thread. Reads x once; writes outX copy and
// the uniform-weight partial record (j=4 channel sums, den=256) for spf0.
__global__ __launch_bounds__(256)
void ssn_init_kernel(const float* __restrict__ x,
                     float* __restrict__ outX,
                     float* __restrict__ wpart) {
    __shared__ float pf_tile[C][PITCH];
    __shared__ float chpart[80];
    int t = threadIdx.x;
    int bi = blockIdx.x;
    int s    = bi & 3;
    int cell = (bi >> 2) & (K - 1);
    int b    = bi >> 10;
    int ky = cell >> 4, kx = cell & 15;
    int py = t >> 5, px = t & 31;
    int y  = ky * 32 + s * 8 + py;
    int xx = kx * 32 + px;

    const float* xb = x    + (size_t)b * C * NPIX + (size_t)y * W + xx;
    float*       ox = outX + (size_t)b * C * NPIX + (size_t)y * W + xx;
#pragma unroll
    for (int ch = 0; ch < C; ++ch) {
        float v = xb[(size_t)ch * NPIX];
        ox[(size_t)ch * NPIX] = v;
        pf_tile[ch][t] = v;
    }
    __syncthreads();
    if (t < 80) {
        int ch = t >> 2, q = t & 3;
        const float4* p = (const float4*)&pf_tile[ch][0];
        float s4 = 0.f;
#pragma unroll
        for (int i = 0; i < 16; ++i) {
            float4 v = p[q * 16 + i];
            s4 += v.x + v.y + v.z + v.w;
        }
        chpart[t] = s4;
    }
    __syncthreads();
    if (t < PART_STRIDE) {
        float v = 0.f;
        if (t >= 84 && t < 104) {
            int ch = t - 84;
            v = chpart[ch * 4] + chpart[ch * 4 + 1]
              + chpart[ch * 4 + 2] + chpart[ch * 4 + 3];
        } else if (t == 104) {
            v = 256.0f;
        }
        wpart[(size_t)(b * K + cell) * (SPLIT * PART_STRIDE)
              + s * PART_STRIDE + t] = v;
    }
}

// ---------------------------------------------------------------- reduce
// One block per (b, cell), 64 threads. Gathers 9 j2 x 4 splits, normalizes,
// writes padded spf row + sumsq@[20]. final_mode: writes outSpf (b,c,k).
__global__ __launch_bounds__(64)
void ssn_reduce_kernel(const float* __restrict__ part,
                       float* __restrict__ spfP,
                       float* __restrict__ outSpf,
                       int final_mode) {
    __shared__ float num_lds[C];
    __shared__ float den_lds;
    __shared__ float sq_lds[C];
    const int t  = threadIdx.x;
    const int bi = blockIdx.x;             // 0..511
    const int cell = bi & (K - 1);
    const int b    = bi >> 8;
    const int ky = cell >> 4, kx = cell & 15;

    if (t <= C) {   // t<20: num for ch=t; t==20: den
        float acc = 0.f;
#pragma unroll
        for (int j2 = 0; j2 < 9; ++j2) {
            int cy = ky - (j2 / 3 - 1), cx = kx - (j2 % 3 - 1);
            if (cy >= 0 && cy < NH && cx >= 0 && cx < NW) {
                const float* p = part +
                    (size_t)((b << 8) + cy * NW + cx) * (SPLIT * PART_STRIDE)
                    + j2 * 21 + t;
#pragma unroll
                for (int ss = 0; ss < SPLIT; ++ss) acc += p[ss * PART_STRIDE];
            }
        }
        if (t < C) num_lds[t] = acc;
        else       den_lds    = acc;
    }
    __syncthreads();
    if (t < C) {
        float v = num_lds[t] / fmaxf(den_lds, 1e-8f);
        if (final_mode) {
            outSpf[((size_t)b * C + t) * K + cell] = v;
        } else {
            spfP[(size_t)bi * SPFP + t] = v;
            sq_lds[t] = v * v;
        }
    }
    __syncthreads();
    if (!final_mode && t == 0) {
        float ss2 = 0.f;
#pragma unroll
        for (int ch = 0; ch < C; ++ch) ss2 += sq_lds[ch];
        spfP[(size_t)bi * SPFP + C] = ss2;
    }
}

// ---------------------------------------------------------------- iterate
// Block = (b, cell, split), 1 px/thread. Phase A reads spf via BLOCK-UNIFORM
// global addresses (scalar loads, no LDS staging, no phase-0 barrier):
// sc_j = 2<pf,spf_j> - |spf_j|^2. Softmax -> w; tiles in LDS; ONE barrier;
// phase B: 9x21 register-tiled dot products -> own split slot.
__global__ __launch_bounds__(256)
void ssn_iterate_kernel(const float* __restrict__ x,
                        const float* __restrict__ spfP,
                        float* __restrict__ wpart,
                        float* __restrict__ outQ,
                        int last) {
    __shared__ float pf_tile[C + 1][PITCH];   // row C = ones (den column)
    __shared__ float w_tile[9][PITCH];

    const int t  = threadIdx.x;
    const int bi = blockIdx.x;
    const int s    = bi & 3;
    const int cell = (bi >> 2) & (K - 1);
    const int b    = bi >> 10;
    const int ky = cell >> 4, kx = cell & 15;
    const int py = t >> 5, px = t & 31;
    const int y  = ky * 32 + s * 8 + py;
    const int xx = kx * 32 + px;

    // per-pixel feature loads (L2/L3-resident after init)
    float pf[C];
    const float* xb = x + (size_t)b * C * NPIX + (size_t)y * W + xx;
#pragma unroll
    for (int ch = 0; ch < C; ++ch) pf[ch] = xb[(size_t)ch * NPIX];

    // ---- phase A: scores from uniform spf rows (SGPR), softmax
    float sc[9];
#pragma unroll
    for (int j = 0; j < 9; ++j) {
        const int ny = ky + j / 3 - 1, nx = kx + j % 3 - 1;
        if (ny >= 0 && ny < NH && nx >= 0 && nx < NW) {   // block-uniform
            const float* sp = spfP + (size_t)((b << 8) + ny * NW + nx) * SPFP;
            float dot = 0.f;
#pragma unroll
            for (int ch = 0; ch < C; ++ch) dot = fmaf(pf[ch], sp[ch], dot);
            sc[j] = fmaf(2.f, dot, -sp[C]);
        } else {
            sc[j] = NEG_INF_F;
        }
    }
    float m = sc[0];
#pragma unroll
    for (int j = 1; j < 9; ++j) m = fmaxf(m, sc[j]);
    float wv[9], wsum = 0.f;
#pragma unroll
    for (int j = 0; j < 9; ++j) { wv[j] = __expf(sc[j] - m); wsum += wv[j]; }
    float inv = 1.0f / wsum;
#pragma unroll
    for (int j = 0; j < 9; ++j) { wv[j] *= inv; w_tile[j][t] = wv[j]; }
#pragma unroll
    for (int ch = 0; ch < C; ++ch) pf_tile[ch][t] = pf[ch];
    pf_tile[C][t] = 1.0f;

    if (last) {
        float* q = outQ + (size_t)b * 9 * NPIX + (size_t)y * W + xx;
#pragma unroll
        for (int j = 0; j < 9; ++j) q[(size_t)j * NPIX] = wv[j];
    }
    __syncthreads();

    // ---- phase B: 9x21 outputs, 3x3 tiles of (3j x 7r), 16 lanes/tile
    if (t < 144) {
        const int tile = t >> 4, lane = t & 15;
        const int jt = tile / 3, rt = tile % 3;
        float acc[3][7];
#pragma unroll
        for (int jj = 0; jj < 3; ++jj)
#pragma unroll
            for (int rr = 0; rr < 7; ++rr) acc[jj][rr] = 0.f;

#pragma unroll
        for (int cc = 0; cc < 4; ++cc) {
            int c4 = lane + (cc << 4);
            float4 w4[3], f4[7];
#pragma unroll
            for (int jj = 0; jj < 3; ++jj)
                w4[jj] = ((const float4*)&w_tile[3 * jt + jj][0])[c4];
#pragma unroll
            for (int rr = 0; rr < 7; ++rr)
                f4[rr] = ((const float4*)&pf_tile[7 * rt + rr][0])[c4];
#pragma unroll
            for (int jj = 0; jj < 3; ++jj)
#pragma unroll
                for (int rr = 0; rr < 7; ++rr) {
                    acc[jj][rr] = fmaf(w4[jj].x, f4[rr].x, acc[jj][rr]);
                    acc[jj][rr] = fmaf(w4[jj].y, f4[rr].y, acc[jj][rr]);
                    acc[jj][rr] = fmaf(w4[jj].z, f4[rr].z, acc[jj][rr]);
                    acc[jj][rr] = fmaf(w4[jj].w, f4[rr].w, acc[jj][rr]);
                }
        }
#pragma unroll
        for (int off = 8; off >= 1; off >>= 1)
#pragma unroll
            for (int jj = 0; jj < 3; ++jj)
#pragma unroll
                for (int rr = 0; rr < 7; ++rr)
                    acc[jj][rr] += __shfl_down(acc[jj][rr], off);
        if (lane == 0) {
            float* dst = wpart + (size_t)((b << 8) + cell) * (SPLIT * PART_STRIDE)
                       + s * PART_STRIDE;
#pragma unroll
            for (int jj = 0; jj < 3; ++jj)
#pragma unroll
                for (int rr = 0; rr < 7; ++rr)
                    dst[(3 * jt + jj) * 21 + 7 * rt + rr] = acc[jj][rr];
        }
    }
}

// ---------------------------------------------------------------- launch
extern "C" void kernel_launch(void* const* d_in, const int* in_sizes, int n_in,
                              void* d_out, int out_size, void* d_ws, size_t ws_size,
                              hipStream_t stream) {
    const float* x = (const float*)d_in[0];
    float* out = (float*)d_out;
    float* outQ   = out;                                   // B*9*NPIX
    float* outSpf = out + (size_t)BATCH * 9 * NPIX;        // B*C*K
    float* outX   = outSpf + (size_t)BATCH * C * K;        // B*C*NPIX

    float* ws   = (float*)d_ws;
    float* part = ws;                                      // B*K*SPLIT*189
    float* spfP = part + (size_t)BATCH * K * SPLIT * PART_STRIDE;  // B*K*32

    ssn_init_kernel<<<BATCH * K * SPLIT, 256, 0, stream>>>(x, outX, part);
    ssn_reduce_kernel<<<BATCH * K, 64, 0, stream>>>(part, spfP, nullptr, 0);

    for (int it = 0; it < NITERS; ++it) {
        ssn_iterate_kernel<<<BATCH * K * SPLIT, 256, 0, stream>>>(
            x, spfP, part, outQ, (it == NITERS - 1) ? 1 : 0);
        if (it < NITERS - 1)
            ssn_reduce_kernel<<<BATCH * K, 64, 0, stream>>>(
                part, spfP, nullptr, 0);
    }
    ssn_reduce_kernel<<<BATCH * K, 64, 0, stream>>>(part, nullptr, outSpf, 1);
}